// Round 2
// baseline (453.289 us; speedup 1.0000x reference)
//
#include <hip/hip_runtime.h>
#include <hip/hip_bf16.h>

#define N    8192
#define INF  256
#define OUTF 128
#define ALPHA 0.2f
#define JS   8               // j-split across blockIdx.y
#define NTS  (N / JS / 32)   // 32 K-steps per block

typedef __attribute__((ext_vector_type(8))) short bf16x8;
typedef __attribute__((ext_vector_type(4))) float f32x4;

__device__ __forceinline__ unsigned short f2bf(float x) {
    union { float f; unsigned u; } v; v.f = x;
    unsigned r = v.u + 0x7fff + ((v.u >> 16) & 1);   // RNE
    return (unsigned short)(r >> 16);
}

// async global->LDS, 16 B per lane (wave-uniform LDS base + lane*16)
__device__ __forceinline__ void gll16(const void* g, void* l) {
    __builtin_amdgcn_global_load_lds(
        (const __attribute__((address_space(1))) unsigned*)g,
        (__attribute__((address_space(3))) unsigned*)l, 16, 0, 0);
}

// mask byte from 8 adjacency ints (adj > 0)
__device__ __forceinline__ unsigned pack8(int4 a, int4 b) {
    return (a.x > 0 ?   1u : 0u) | (a.y > 0 ?   2u : 0u)
         | (a.z > 0 ?   4u : 0u) | (a.w > 0 ?   8u : 0u)
         | (b.x > 0 ?  16u : 0u) | (b.y > 0 ?  32u : 0u)
         | (b.z > 0 ?  64u : 0u) | (b.w > 0 ? 128u : 0u);
}

// ---------------- Kernel 1: WhT_b = blocked bf16 (h@W)^T ; f1 ; f2 ----------
// (bit-pack pass deleted this round: k2 tiles adj exactly once, so the mask
//  indirection saved no traffic — it only serialized a 268 MB pass.)
__global__ __launch_bounds__(256) void k1_prep(
        const float* __restrict__ h, const float* __restrict__ W,
        const float* __restrict__ a,
        unsigned short* __restrict__ WhTb, float* __restrict__ f1, float* __restrict__ f2) {
    __shared__ float hs[8][INF];          // 8 KB
    const int t = threadIdx.x;

    const int i0 = blockIdx.x * 8;
    #pragma unroll
    for (int u = 0; u < 2; ++u) {
        int idx = u * 256 + t;
        int r   = idx >> 6;               // 0..7 (wave-uniform)
        int kq  = idx & 63;
        *(float4*)&hs[r][kq * 4] = *(const float4*)(h + (size_t)(i0 + r) * INF + kq * 4);
    }
    __syncthreads();

    const int rg = t >> 5;                // 0..7 : row
    const int ct = t & 31;                // 0..31 : col group
    float acc[4] = {0.f, 0.f, 0.f, 0.f};

    #pragma unroll 8
    for (int k = 0; k < INF; ++k) {
        float4 wv = *(const float4*)(W + (size_t)k * OUTF + ct * 4);
        float  hx = hs[rg][k];
        acc[0] += hx * wv.x; acc[1] += hx * wv.y;
        acc[2] += hx * wv.z; acc[3] += hx * wv.w;
    }

    const int r0 = i0 + rg;               // j index
    const int jb = r0 >> 5;
    const int jo = r0 & 31;
    #pragma unroll
    for (int cc = 0; cc < 4; ++cc)
        WhTb[(size_t)jb * 4096 + (ct * 4 + cc) * 32 + jo] = f2bf(acc[cc]);

    const float4 a1v = *(const float4*)(a + ct * 4);
    const float4 a2v = *(const float4*)(a + OUTF + ct * 4);
    float p1 = acc[0]*a1v.x + acc[1]*a1v.y + acc[2]*a1v.z + acc[3]*a1v.w;
    float p2 = acc[0]*a2v.x + acc[1]*a2v.y + acc[2]*a2v.z + acc[3]*a2v.w;
    #pragma unroll
    for (int off = 16; off > 0; off >>= 1) {
        p1 += __shfl_down(p1, off, 32);
        p2 += __shfl_down(p2, off, 32);
    }
    if (ct == 0) { f1[r0] = p1; f2[r0] = p2; }
}

// ---------------- Kernel 2: MFMA attention, adj streamed in-kernel ----------
// Each lane reads its own 8 adj ints (2 x int4, 32 B) one step ahead and
// packs them to a mask byte at step bottom (1 live VGPR across steps).
// Each (i,s) block covers a distinct 64x1024 adj tile -> adj read exactly
// once, inside the compute kernel: the separate 268 MB bit-pack pass is gone.
// k2 is now HBM-bound on the adj stream (~43 us floor); LDS/MFMA/VALU all
// model at <=20 us and hide underneath.
// vmcnt discipline (re-derived with adj loads counted): per-step issue order
// is [adj(jt+1) x2, gll16(jt+2) x2]; younger-than-g(jt) at step jt's barrier
// is <=6 for every step (incl. step 0, where the prologue issues only 2
// future tiles) -> "s_waitcnt vmcnt(6); s_barrier". Step 31: vmcnt(2).
// Compiler waits for the adj registers are strictly tighter, so any
// intra-step reorder keeps these conservative.
__device__ __forceinline__ float pbit(float f1r, float fv, unsigned byte_,
                                      int u, float& dsum) {
    float s = f1r + fv;
    float e = fmaxf(s, ALPHA * s);        // leaky-relu, branch-free
    float p = (byte_ & (1u << u)) ? __expf(e) : 0.f;
    dsum += p;
    return p;
}

#define VMB6 "s_waitcnt vmcnt(6)\n\ts_barrier"
#define VMB2 "s_waitcnt vmcnt(2)\n\ts_barrier"

// O = compile-time step-phase (0..3) -> buffer O, prefetch into (O+2)&3.
// JT = runtime K-step index. ISSG/ISSA compile-time flags.
#define K2STEP(O, JT, VMB, ISSG, ISSA)                                       \
    {                                                                        \
        int4 na_ = {}, nb_ = {};                                             \
        if (ISSA) { na_ = arow[((JT) + 1) * 8]; nb_ = arow[((JT) + 1) * 8 + 1]; } \
        if (ISSG) {                                                          \
            const char* ws_ = (const char*)WhTb + (size_t)(tile0 + (JT) + 2) * 8192; \
            char* bd_ = (char*)&bsm[((O) + 2) & 3][0];                       \
            gll16(ws_ + tsw,        bd_ + wv * 1024);                        \
            gll16(ws_ + 4096 + tsw, bd_ + 4096 + wv * 1024);                 \
        }                                                                    \
        float4 F0_ = *(const float4*)&f2s[(JT) * 32 + quad * 8];             \
        float4 F1_ = *(const float4*)&f2s[(JT) * 32 + quad * 8 + 4];         \
        unsigned byte_ = byteC;                                              \
        float p0_ = pbit(f1r, F0_.x, byte_, 0, dsum);                        \
        float p1_ = pbit(f1r, F0_.y, byte_, 1, dsum);                        \
        float p2_ = pbit(f1r, F0_.z, byte_, 2, dsum);                        \
        float p3_ = pbit(f1r, F0_.w, byte_, 3, dsum);                        \
        float p4_ = pbit(f1r, F1_.x, byte_, 4, dsum);                        \
        float p5_ = pbit(f1r, F1_.y, byte_, 5, dsum);                        \
        float p6_ = pbit(f1r, F1_.z, byte_, 6, dsum);                        \
        float p7_ = pbit(f1r, F1_.w, byte_, 7, dsum);                        \
        union { __hip_bfloat162 hh[4]; bf16x8 v; } pk_;                      \
        pk_.hh[0] = __float22bfloat162_rn(make_float2(p0_, p1_));            \
        pk_.hh[1] = __float22bfloat162_rn(make_float2(p2_, p3_));            \
        pk_.hh[2] = __float22bfloat162_rn(make_float2(p4_, p5_));            \
        pk_.hh[3] = __float22bfloat162_rn(make_float2(p6_, p7_));            \
        bf16x8 afrag = pk_.v;                                                \
        asm volatile(VMB ::: "memory");                                      \
        const char* bb_ = (const char*)&bsm[(O)][0] + laneb2;                \
        bf16x8 b0_ = *(const bf16x8*)(bb_);                                  \
        bf16x8 b1_ = *(const bf16x8*)(bb_ + 1024);                           \
        bf16x8 b2_ = *(const bf16x8*)(bb_ + 2048);                           \
        bf16x8 b3_ = *(const bf16x8*)(bb_ + 3072);                           \
        bf16x8 b4_ = *(const bf16x8*)(bb_ + 4096);                           \
        bf16x8 b5_ = *(const bf16x8*)(bb_ + 5120);                           \
        bf16x8 b6_ = *(const bf16x8*)(bb_ + 6144);                           \
        bf16x8 b7_ = *(const bf16x8*)(bb_ + 7168);                           \
        acc0 = __builtin_amdgcn_mfma_f32_16x16x32_bf16(afrag, b0_, acc0, 0, 0, 0); \
        acc1 = __builtin_amdgcn_mfma_f32_16x16x32_bf16(afrag, b1_, acc1, 0, 0, 0); \
        acc2 = __builtin_amdgcn_mfma_f32_16x16x32_bf16(afrag, b2_, acc2, 0, 0, 0); \
        acc3 = __builtin_amdgcn_mfma_f32_16x16x32_bf16(afrag, b3_, acc3, 0, 0, 0); \
        acc4 = __builtin_amdgcn_mfma_f32_16x16x32_bf16(afrag, b4_, acc4, 0, 0, 0); \
        acc5 = __builtin_amdgcn_mfma_f32_16x16x32_bf16(afrag, b5_, acc5, 0, 0, 0); \
        acc6 = __builtin_amdgcn_mfma_f32_16x16x32_bf16(afrag, b6_, acc6, 0, 0, 0); \
        acc7 = __builtin_amdgcn_mfma_f32_16x16x32_bf16(afrag, b7_, acc7, 0, 0, 0); \
        if (ISSA) byteC = pack8(na_, nb_);                                   \
    }

__global__ __launch_bounds__(256, 4) void k2_attn(
        const int* __restrict__ adj, const unsigned short* __restrict__ WhTb,
        const float* __restrict__ f1, const float* __restrict__ f2,
        float* __restrict__ num, float* __restrict__ den) {
    __shared__ unsigned short bsm[4][4096];   // 4 x 8 KB B-tile ring buffer
    __shared__ float f2s[1024];               // block's f2 span (4 KB)

    const int t    = threadIdx.x;
    const int wv   = t >> 6;              // 0..3 : wave -> row-tile
    const int ln   = t & 63;
    const int m16  = ln & 15;
    const int quad = ln >> 4;
    const int i0   = blockIdx.x * 64;
    const int s    = blockIdx.y;
    const int row  = i0 + wv * 16 + m16;
    const int tile0 = s * NTS;
    const int j0    = s * (N / JS);
    // B-fragment read offset (swizzle kept from r0; verified correct)
    const int laneb2 = m16 * 64 + ((quad ^ ((m16 >> 1) & 3)) << 4);
    // staging SOURCE offset (involution of dst byte t*16)
    const int tsw = (t * 16) ^ (((t >> 3) & 3) << 4);

    // lane's adjacency segment: 8 consecutive ints per step
    const int4* arow = (const int4*)(adj + (size_t)row * N + j0 + quad * 8);

    // adj for step 0, f2 span, B tiles 0,1 (all async / in flight)
    int4 na0 = arow[0], nb0 = arow[1];
    *(float4*)&f2s[t * 4] = *(const float4*)(f2 + j0 + t * 4);
    {
        const char* ws0 = (const char*)WhTb + (size_t)tile0 * 8192;
        char* bd0 = (char*)&bsm[0][0];
        gll16(ws0 + tsw,        bd0 + wv * 1024);
        gll16(ws0 + 4096 + tsw, bd0 + 4096 + wv * 1024);
        const char* ws1 = ws0 + 8192;
        char* bd1 = (char*)&bsm[1][0];
        gll16(ws1 + tsw,        bd1 + wv * 1024);
        gll16(ws1 + 4096 + tsw, bd1 + 4096 + wv * 1024);
    }

    const float f1r = f1[row];

    f32x4 acc0 = {0.f,0.f,0.f,0.f}, acc1 = {0.f,0.f,0.f,0.f};
    f32x4 acc2 = {0.f,0.f,0.f,0.f}, acc3 = {0.f,0.f,0.f,0.f};
    f32x4 acc4 = {0.f,0.f,0.f,0.f}, acc5 = {0.f,0.f,0.f,0.f};
    f32x4 acc6 = {0.f,0.f,0.f,0.f}, acc7 = {0.f,0.f,0.f,0.f};
    float dsum = 0.f;

    unsigned byteC = pack8(na0, nb0);     // waits adj(0) only; tiles stay in flight
    // f2s visible to all waves; do NOT drain vmcnt (tiles 0,1 in flight)
    asm volatile("s_waitcnt lgkmcnt(0)\n\ts_barrier" ::: "memory");

    for (int g = 0; g < 7; ++g) {         // 7 full groups x 4 steps
        const int jtb = g * 4;
        K2STEP(0, jtb + 0, VMB6, 1, 1)
        K2STEP(1, jtb + 1, VMB6, 1, 1)
        K2STEP(2, jtb + 2, VMB6, 1, 1)
        K2STEP(3, jtb + 3, VMB6, 1, 1)
    }
    // tail group (steps 28..31): last gll16 issues are tiles 30,31
    K2STEP(0, 28, VMB6, 1, 1)
    K2STEP(1, 29, VMB6, 1, 1)
    K2STEP(2, 30, VMB6, 0, 1)
    K2STEP(3, 31, VMB2, 0, 0)

    // den partial: sum the 4 quads of each row
    dsum += __shfl_xor(dsum, 16);
    dsum += __shfl_xor(dsum, 32);
    if (quad == 0) den[(size_t)s * N + row] = dsum;

    // num partial: D layout col=lane&15, row=quad*4+reg
    float* np = num + (size_t)s * N * OUTF;
    #pragma unroll
    for (int r = 0; r < 4; ++r) {
        const size_t orow = (size_t)(i0 + wv * 16 + quad * 4 + r) * OUTF;
        np[orow + 0 * 16 + m16] = acc0[r];
        np[orow + 1 * 16 + m16] = acc1[r];
        np[orow + 2 * 16 + m16] = acc2[r];
        np[orow + 3 * 16 + m16] = acc3[r];
        np[orow + 4 * 16 + m16] = acc4[r];
        np[orow + 5 * 16 + m16] = acc5[r];
        np[orow + 6 * 16 + m16] = acc6[r];
        np[orow + 7 * 16 + m16] = acc7[r];
    }
}

// ---------------- Kernel 3: combine JS partials, normalize ----------------
__global__ __launch_bounds__(256) void k3_combine(
        const float* __restrict__ num, const float* __restrict__ den,
        float* __restrict__ out) {
    const int idx = blockIdx.x * 256 + threadIdx.x;   // float4 index
    const int row = idx >> 5;
    const int c4  = (idx & 31) * 4;
    float4 ns = {0.f,0.f,0.f,0.f};
    float  ds = 0.f;
    #pragma unroll
    for (int s = 0; s < JS; ++s) {
        float4 nv = *(const float4*)(num + ((size_t)s * N + row) * OUTF + c4);
        ns.x += nv.x; ns.y += nv.y; ns.z += nv.z; ns.w += nv.w;
        ds += den[(size_t)s * N + row];
    }
    const float inv = 1.0f / ds;
    float4 o = {ns.x * inv, ns.y * inv, ns.z * inv, ns.w * inv};
    *(float4*)(out + (size_t)row * OUTF + c4) = o;
}

extern "C" void kernel_launch(void* const* d_in, const int* in_sizes, int n_in,
                              void* d_out, int out_size, void* d_ws, size_t ws_size,
                              hipStream_t stream) {
    const float* h   = (const float*)d_in[0];   // (8192, 256)
    const int*   adj = (const int*)  d_in[1];   // (8192, 8192)
    const float* W   = (const float*)d_in[2];   // (256, 128)
    const float* a   = (const float*)d_in[3];   // (256, 1)
    float* out = (float*)d_out;                 // (8192, 128)

    unsigned short* WhTb = (unsigned short*)d_ws;          // 2 MB blocked bf16
    float*    f1   = (float*)(WhTb + (size_t)N * OUTF);    // 32 KB
    float*    f2   = f1 + N;                               // 32 KB
    float*    den  = f2 + N;                               // JS*N = 256 KB
    float*    num  = den + (size_t)JS * N;                 // JS*N*OUTF = 32 MB

    k1_prep   <<<N / 8, 256, 0, stream>>>(h, W, a, WhTb, f1, f2);
    k2_attn   <<<dim3(N / 64, JS), 256, 0, stream>>>(adj, WhTb, f1, f2, num, den);
    k3_combine<<<(N * OUTF / 4) / 256, 256, 0, stream>>>(num, den, out);
}

// Round 3
// 449.506 us; speedup vs baseline: 1.0084x; 1.0084x over previous
//
#include <hip/hip_runtime.h>
#include <hip/hip_bf16.h>

#define N    8192
#define INF  256
#define OUTF 128
#define ALPHA 0.2f
#define JS   8               // j-split across blockIdx.y
#define NTS  (N / JS / 32)   // 32 K-steps per block

typedef __attribute__((ext_vector_type(8))) short bf16x8;
typedef __attribute__((ext_vector_type(4))) float f32x4;

__device__ __forceinline__ unsigned short f2bf(float x) {
    union { float f; unsigned u; } v; v.f = x;
    unsigned r = v.u + 0x7fff + ((v.u >> 16) & 1);   // RNE
    return (unsigned short)(r >> 16);
}

// async global->LDS, 16 B per lane (wave-uniform LDS base + lane*16)
__device__ __forceinline__ void gll16(const void* g, void* l) {
    __builtin_amdgcn_global_load_lds(
        (const __attribute__((address_space(1))) unsigned*)g,
        (__attribute__((address_space(3))) unsigned*)l, 16, 0, 0);
}

// mask byte from 8 adjacency ints (adj > 0)
__device__ __forceinline__ unsigned pack8(int4 a, int4 b) {
    return (a.x > 0 ?   1u : 0u) | (a.y > 0 ?   2u : 0u)
         | (a.z > 0 ?   4u : 0u) | (a.w > 0 ?   8u : 0u)
         | (b.x > 0 ?  16u : 0u) | (b.y > 0 ?  32u : 0u)
         | (b.z > 0 ?  64u : 0u) | (b.w > 0 ? 128u : 0u);
}

// ---------------- Kernel 1: WhT_b = blocked bf16 (h@W)^T ; f1 ; f2 ----------
__global__ __launch_bounds__(256) void k1_prep(
        const float* __restrict__ h, const float* __restrict__ W,
        const float* __restrict__ a,
        unsigned short* __restrict__ WhTb, float* __restrict__ f1, float* __restrict__ f2) {
    __shared__ float hs[8][INF];          // 8 KB
    const int t = threadIdx.x;

    const int i0 = blockIdx.x * 8;
    #pragma unroll
    for (int u = 0; u < 2; ++u) {
        int idx = u * 256 + t;
        int r   = idx >> 6;               // 0..7 (wave-uniform)
        int kq  = idx & 63;
        *(float4*)&hs[r][kq * 4] = *(const float4*)(h + (size_t)(i0 + r) * INF + kq * 4);
    }
    __syncthreads();

    const int rg = t >> 5;                // 0..7 : row
    const int ct = t & 31;                // 0..31 : col group
    float acc[4] = {0.f, 0.f, 0.f, 0.f};

    #pragma unroll 8
    for (int k = 0; k < INF; ++k) {
        float4 wv = *(const float4*)(W + (size_t)k * OUTF + ct * 4);
        float  hx = hs[rg][k];
        acc[0] += hx * wv.x; acc[1] += hx * wv.y;
        acc[2] += hx * wv.z; acc[3] += hx * wv.w;
    }

    const int r0 = i0 + rg;               // j index
    const int jb = r0 >> 5;
    const int jo = r0 & 31;
    #pragma unroll
    for (int cc = 0; cc < 4; ++cc)
        WhTb[(size_t)jb * 4096 + (ct * 4 + cc) * 32 + jo] = f2bf(acc[cc]);

    const float4 a1v = *(const float4*)(a + ct * 4);
    const float4 a2v = *(const float4*)(a + OUTF + ct * 4);
    float p1 = acc[0]*a1v.x + acc[1]*a1v.y + acc[2]*a1v.z + acc[3]*a1v.w;
    float p2 = acc[0]*a2v.x + acc[1]*a2v.y + acc[2]*a2v.z + acc[3]*a2v.w;
    #pragma unroll
    for (int off = 16; off > 0; off >>= 1) {
        p1 += __shfl_down(p1, off, 32);
        p2 += __shfl_down(p2, off, 32);
    }
    if (ct == 0) { f1[r0] = p1; f2[r0] = p2; }
}

// ---------------- Kernel 2: MFMA attention, adj streamed in-kernel ----------
// Round-2 regression root cause: adj consumed in the SAME step it was issued
// -> compiler's register wait (vmcnt<=2) drained the async tile pipeline
// every step. Fix: 2-step adj register prefetch with parity register sets.
//   step jt top   : issue adj(jt+2) into set[jt&1]            (fire & forget)
//   step jt bottom: byteC(for step jt+1) = pack8(set[(jt+1)&1])  [adj(jt+1),
//                   issued at step jt-1 -> >=6 younger VMEM ops at the wait,
//                   so the compiler wait is vmcnt(6)-class: no tile drain]
// Barrier waits re-proved robust to any intra-segment issue reorder (asm
// "memory" fences bound each step): steps>=1 outstanding ⊆ {g(jt)x2} ∪ 8
// younger -> vmcnt(8); step 0 prologue-ambiguous -> vmcnt(4); tail 30/31 ->
// vmcnt(4)/vmcnt(0). vmcnt-before-barrier covers cross-wave DMA (m201).
__device__ __forceinline__ float pbit(float f1r, float fv, unsigned byte_,
                                      int u, float& dsum) {
    float s = f1r + fv;
    float e = fmaxf(s, ALPHA * s);        // leaky-relu, branch-free
    float p = (byte_ & (1u << u)) ? __expf(e) : 0.f;
    dsum += p;
    return p;
}

#define VMB8 "s_waitcnt vmcnt(8)\n\ts_barrier"
#define VMB4 "s_waitcnt vmcnt(4)\n\ts_barrier"
#define VMB0 "s_waitcnt vmcnt(0)\n\ts_barrier"

// O = compile-time step-phase (0..3): buffer O, prefetch tile into (O+2)&3,
// adj set parity O&1. JT = runtime K-step index. ISSG/ISSA/PACK compile-time.
#define K2STEP(O, JT, VMB, ISSG, ISSA, PACK)                                 \
    {                                                                        \
        if (ISSA) {                                                          \
            if (((O) & 1) == 0) { naA = arow[((JT) + 2) * 8]; nbA = arow[((JT) + 2) * 8 + 1]; } \
            else                { naB = arow[((JT) + 2) * 8]; nbB = arow[((JT) + 2) * 8 + 1]; } \
        }                                                                    \
        if (ISSG) {                                                          \
            const char* ws_ = (const char*)WhTb + (size_t)(tile0 + (JT) + 2) * 8192; \
            char* bd_ = (char*)&bsm[((O) + 2) & 3][0];                       \
            gll16(ws_ + tsw,        bd_ + wv * 1024);                        \
            gll16(ws_ + 4096 + tsw, bd_ + 4096 + wv * 1024);                 \
        }                                                                    \
        float4 F0_ = *(const float4*)&f2s[(JT) * 32 + quad * 8];             \
        float4 F1_ = *(const float4*)&f2s[(JT) * 32 + quad * 8 + 4];         \
        unsigned byte_ = byteC;                                              \
        float p0_ = pbit(f1r, F0_.x, byte_, 0, dsum);                        \
        float p1_ = pbit(f1r, F0_.y, byte_, 1, dsum);                        \
        float p2_ = pbit(f1r, F0_.z, byte_, 2, dsum);                        \
        float p3_ = pbit(f1r, F0_.w, byte_, 3, dsum);                        \
        float p4_ = pbit(f1r, F1_.x, byte_, 4, dsum);                        \
        float p5_ = pbit(f1r, F1_.y, byte_, 5, dsum);                        \
        float p6_ = pbit(f1r, F1_.z, byte_, 6, dsum);                        \
        float p7_ = pbit(f1r, F1_.w, byte_, 7, dsum);                        \
        union { __hip_bfloat162 hh[4]; bf16x8 v; } pk_;                      \
        pk_.hh[0] = __float22bfloat162_rn(make_float2(p0_, p1_));            \
        pk_.hh[1] = __float22bfloat162_rn(make_float2(p2_, p3_));            \
        pk_.hh[2] = __float22bfloat162_rn(make_float2(p4_, p5_));            \
        pk_.hh[3] = __float22bfloat162_rn(make_float2(p6_, p7_));            \
        bf16x8 afrag = pk_.v;                                                \
        asm volatile(VMB ::: "memory");                                      \
        const char* bb_ = (const char*)&bsm[(O)][0] + laneb2;                \
        bf16x8 b0_ = *(const bf16x8*)(bb_);                                  \
        bf16x8 b1_ = *(const bf16x8*)(bb_ + 1024);                           \
        bf16x8 b2_ = *(const bf16x8*)(bb_ + 2048);                           \
        bf16x8 b3_ = *(const bf16x8*)(bb_ + 3072);                           \
        bf16x8 b4_ = *(const bf16x8*)(bb_ + 4096);                           \
        bf16x8 b5_ = *(const bf16x8*)(bb_ + 5120);                           \
        bf16x8 b6_ = *(const bf16x8*)(bb_ + 6144);                           \
        bf16x8 b7_ = *(const bf16x8*)(bb_ + 7168);                           \
        acc0 = __builtin_amdgcn_mfma_f32_16x16x32_bf16(afrag, b0_, acc0, 0, 0, 0); \
        acc1 = __builtin_amdgcn_mfma_f32_16x16x32_bf16(afrag, b1_, acc1, 0, 0, 0); \
        acc2 = __builtin_amdgcn_mfma_f32_16x16x32_bf16(afrag, b2_, acc2, 0, 0, 0); \
        acc3 = __builtin_amdgcn_mfma_f32_16x16x32_bf16(afrag, b3_, acc3, 0, 0, 0); \
        acc4 = __builtin_amdgcn_mfma_f32_16x16x32_bf16(afrag, b4_, acc4, 0, 0, 0); \
        acc5 = __builtin_amdgcn_mfma_f32_16x16x32_bf16(afrag, b5_, acc5, 0, 0, 0); \
        acc6 = __builtin_amdgcn_mfma_f32_16x16x32_bf16(afrag, b6_, acc6, 0, 0, 0); \
        acc7 = __builtin_amdgcn_mfma_f32_16x16x32_bf16(afrag, b7_, acc7, 0, 0, 0); \
        if (PACK) byteC = (((O) & 1) == 0) ? pack8(naB, nbB) : pack8(naA, nbA); \
    }

__global__ __launch_bounds__(256, 4) void k2_attn(
        const int* __restrict__ adj, const unsigned short* __restrict__ WhTb,
        const float* __restrict__ f1, const float* __restrict__ f2,
        float* __restrict__ num, float* __restrict__ den) {
    __shared__ unsigned short bsm[4][4096];   // 4 x 8 KB B-tile ring buffer
    __shared__ float f2s[1024];               // block's f2 span (4 KB)

    const int t    = threadIdx.x;
    const int wv   = t >> 6;              // 0..3 : wave -> row-tile
    const int ln   = t & 63;
    const int m16  = ln & 15;
    const int quad = ln >> 4;
    const int i0   = blockIdx.x * 64;
    const int s    = blockIdx.y;
    const int row  = i0 + wv * 16 + m16;
    const int tile0 = s * NTS;
    const int j0    = s * (N / JS);
    // B-fragment read offset (swizzled; verified)
    const int laneb2 = m16 * 64 + ((quad ^ ((m16 >> 1) & 3)) << 4);
    // staging SOURCE offset (involution of dst byte t*16)
    const int tsw = (t * 16) ^ (((t >> 3) & 3) << 4);

    // lane's adjacency segment: 8 consecutive ints per step
    const int4* arow = (const int4*)(adj + (size_t)row * N + j0 + quad * 8);

    // adj prefetch register sets (parity by step)
    int4 naA, nbA, naB, nbB;

    // prologue: adj(0) (consumed here), adj(1)->setB, f2 span, tiles 0,1
    int4 t0a = arow[0], t0b = arow[1];
    naB = arow[8]; nbB = arow[9];
    *(float4*)&f2s[t * 4] = *(const float4*)(f2 + j0 + t * 4);
    {
        const char* ws0 = (const char*)WhTb + (size_t)tile0 * 8192;
        char* bd0 = (char*)&bsm[0][0];
        gll16(ws0 + tsw,        bd0 + wv * 1024);
        gll16(ws0 + 4096 + tsw, bd0 + 4096 + wv * 1024);
        const char* ws1 = ws0 + 8192;
        char* bd1 = (char*)&bsm[1][0];
        gll16(ws1 + tsw,        bd1 + wv * 1024);
        gll16(ws1 + 4096 + tsw, bd1 + 4096 + wv * 1024);
    }

    const float f1r = f1[row];

    f32x4 acc0 = {0.f,0.f,0.f,0.f}, acc1 = {0.f,0.f,0.f,0.f};
    f32x4 acc2 = {0.f,0.f,0.f,0.f}, acc3 = {0.f,0.f,0.f,0.f};
    f32x4 acc4 = {0.f,0.f,0.f,0.f}, acc5 = {0.f,0.f,0.f,0.f};
    f32x4 acc6 = {0.f,0.f,0.f,0.f}, acc7 = {0.f,0.f,0.f,0.f};
    float dsum = 0.f;

    unsigned byteC = pack8(t0a, t0b);     // step-0 mask (prologue one-time wait)
    // f2s visible to all waves; tiles 0,1 + adj(1) stay in flight
    asm volatile("s_waitcnt lgkmcnt(0)\n\ts_barrier" ::: "memory");

    // step 0 peeled: prologue issue order compiler-ambiguous -> vmcnt(4)
    K2STEP(0, 0, VMB4, 1, 1, 1)
    K2STEP(1, 1, VMB8, 1, 1, 1)
    K2STEP(2, 2, VMB8, 1, 1, 1)
    K2STEP(3, 3, VMB8, 1, 1, 1)

    for (int g = 1; g < 7; ++g) {         // steps 4..27
        const int jtb = g * 4;
        K2STEP(0, jtb + 0, VMB8, 1, 1, 1)
        K2STEP(1, jtb + 1, VMB8, 1, 1, 1)
        K2STEP(2, jtb + 2, VMB8, 1, 1, 1)
        K2STEP(3, jtb + 3, VMB8, 1, 1, 1)
    }
    // tail: steps 28..31 (last gll16 at 29 -> tile 31; last adj at 29 -> adj(31))
    K2STEP(0, 28, VMB8, 1, 1, 1)
    K2STEP(1, 29, VMB8, 1, 1, 1)
    K2STEP(2, 30, VMB4, 0, 0, 1)
    K2STEP(3, 31, VMB0, 0, 0, 0)

    // den partial: sum the 4 quads of each row
    dsum += __shfl_xor(dsum, 16);
    dsum += __shfl_xor(dsum, 32);
    if (quad == 0) den[(size_t)s * N + row] = dsum;

    // num partial: D layout col=lane&15, row=quad*4+reg
    float* np = num + (size_t)s * N * OUTF;
    #pragma unroll
    for (int r = 0; r < 4; ++r) {
        const size_t orow = (size_t)(i0 + wv * 16 + quad * 4 + r) * OUTF;
        np[orow + 0 * 16 + m16] = acc0[r];
        np[orow + 1 * 16 + m16] = acc1[r];
        np[orow + 2 * 16 + m16] = acc2[r];
        np[orow + 3 * 16 + m16] = acc3[r];
        np[orow + 4 * 16 + m16] = acc4[r];
        np[orow + 5 * 16 + m16] = acc5[r];
        np[orow + 6 * 16 + m16] = acc6[r];
        np[orow + 7 * 16 + m16] = acc7[r];
    }
}

// ---------------- Kernel 3: combine JS partials, normalize ----------------
__global__ __launch_bounds__(256) void k3_combine(
        const float* __restrict__ num, const float* __restrict__ den,
        float* __restrict__ out) {
    const int idx = blockIdx.x * 256 + threadIdx.x;   // float4 index
    const int row = idx >> 5;
    const int c4  = (idx & 31) * 4;
    float4 ns = {0.f,0.f,0.f,0.f};
    float  ds = 0.f;
    #pragma unroll
    for (int s = 0; s < JS; ++s) {
        float4 nv = *(const float4*)(num + ((size_t)s * N + row) * OUTF + c4);
        ns.x += nv.x; ns.y += nv.y; ns.z += nv.z; ns.w += nv.w;
        ds += den[(size_t)s * N + row];
    }
    const float inv = 1.0f / ds;
    float4 o = {ns.x * inv, ns.y * inv, ns.z * inv, ns.w * inv};
    *(float4*)(out + (size_t)row * OUTF + c4) = o;
}

extern "C" void kernel_launch(void* const* d_in, const int* in_sizes, int n_in,
                              void* d_out, int out_size, void* d_ws, size_t ws_size,
                              hipStream_t stream) {
    const float* h   = (const float*)d_in[0];   // (8192, 256)
    const int*   adj = (const int*)  d_in[1];   // (8192, 8192)
    const float* W   = (const float*)d_in[2];   // (256, 128)
    const float* a   = (const float*)d_in[3];   // (256, 1)
    float* out = (float*)d_out;                 // (8192, 128)

    unsigned short* WhTb = (unsigned short*)d_ws;          // 2 MB blocked bf16
    float*    f1   = (float*)(WhTb + (size_t)N * OUTF);    // 32 KB
    float*    f2   = f1 + N;                               // 32 KB
    float*    den  = f2 + N;                               // JS*N = 256 KB
    float*    num  = den + (size_t)JS * N;                 // JS*N*OUTF = 32 MB

    k1_prep   <<<N / 8, 256, 0, stream>>>(h, W, a, WhTb, f1, f2);
    k2_attn   <<<dim3(N / 64, JS), 256, 0, stream>>>(adj, WhTb, f1, f2, num, den);
    k3_combine<<<(N * OUTF / 4) / 256, 256, 0, stream>>>(num, den, out);
}

// Round 5
// 431.825 us; speedup vs baseline: 1.0497x; 1.0409x over previous
//
#include <hip/hip_runtime.h>
#include <hip/hip_bf16.h>

#define N    8192
#define INF  256
#define OUTF 128
#define ALPHA 0.2f
#define JS   8               // j-split across blockIdx.y
#define NTS  (N / JS / 32)   // 32 K-steps per block

typedef __attribute__((ext_vector_type(8))) short bf16x8;
typedef __attribute__((ext_vector_type(4))) float f32x4;

__device__ __forceinline__ unsigned short f2bf(float x) {
    union { float f; unsigned u; } v; v.f = x;
    unsigned r = v.u + 0x7fff + ((v.u >> 16) & 1);   // RNE
    return (unsigned short)(r >> 16);
}

// async global->LDS, 16 B per lane (wave-uniform LDS base + lane*16)
__device__ __forceinline__ void gll16(const void* g, void* l) {
    __builtin_amdgcn_global_load_lds(
        (const __attribute__((address_space(1))) unsigned*)g,
        (__attribute__((address_space(3))) unsigned*)l, 16, 0, 0);
}

// ---------------- Kernel 0+1 fused (r1 structure restored) ------------------
// Blocks [0,1024): k1 body — WhT_b = blocked bf16 (h@W)^T ; f1 ; f2.
// Blocks [1024,9216): k0 body — bit-pack adj (268 MB -> 8 MB), coalesced.
// adj must be read once somewhere; the dedicated packer streams it at 84%
// of peak (measured), far better than a barrier-locked MFMA loop can.
__global__ __launch_bounds__(256) void k01_prep(
        const int* __restrict__ adj, unsigned* __restrict__ bits,
        const float* __restrict__ h, const float* __restrict__ W,
        const float* __restrict__ a,
        unsigned short* __restrict__ WhTb, float* __restrict__ f1, float* __restrict__ f2) {
    __shared__ float hs[8][INF];          // 8 KB (k1 blocks only)
    const int t = threadIdx.x;

    if (blockIdx.x >= 1024) {
        // ---- k0: pack 32 adj ints -> 1 bit word per thread ----
        const size_t g = (size_t)(blockIdx.x - 1024) * 256 + t;   // word idx, 2M
        const int4* p = (const int4*)adj + g * 8;
        unsigned b = 0;
        #pragma unroll
        for (int u = 0; u < 8; ++u) {
            int4 v = p[u];
            b |= (v.x > 0 ? 1u : 0u) << (u * 4 + 0);
            b |= (v.y > 0 ? 1u : 0u) << (u * 4 + 1);
            b |= (v.z > 0 ? 1u : 0u) << (u * 4 + 2);
            b |= (v.w > 0 ? 1u : 0u) << (u * 4 + 3);
        }
        bits[g] = b;
        return;
    }

    // ---- k1: 8 rows/block ----
    const int i0 = blockIdx.x * 8;
    #pragma unroll
    for (int u = 0; u < 2; ++u) {
        int idx = u * 256 + t;
        int r   = idx >> 6;               // 0..7 (wave-uniform)
        int kq  = idx & 63;
        *(float4*)&hs[r][kq * 4] = *(const float4*)(h + (size_t)(i0 + r) * INF + kq * 4);
    }
    __syncthreads();

    const int rg = t >> 5;                // 0..7 : row
    const int ct = t & 31;                // 0..31 : col group
    float acc[4] = {0.f, 0.f, 0.f, 0.f};

    #pragma unroll 8
    for (int k = 0; k < INF; ++k) {
        float4 wv = *(const float4*)(W + (size_t)k * OUTF + ct * 4);
        float  hx = hs[rg][k];
        acc[0] += hx * wv.x; acc[1] += hx * wv.y;
        acc[2] += hx * wv.z; acc[3] += hx * wv.w;
    }

    const int r0 = i0 + rg;               // j index
    const int jb = r0 >> 5;
    const int jo = r0 & 31;
    #pragma unroll
    for (int cc = 0; cc < 4; ++cc)
        WhTb[(size_t)jb * 4096 + (ct * 4 + cc) * 32 + jo] = f2bf(acc[cc]);

    const float4 a1v = *(const float4*)(a + ct * 4);
    const float4 a2v = *(const float4*)(a + OUTF + ct * 4);
    float p1 = acc[0]*a1v.x + acc[1]*a1v.y + acc[2]*a1v.z + acc[3]*a1v.w;
    float p2 = acc[0]*a2v.x + acc[1]*a2v.y + acc[2]*a2v.z + acc[3]*a2v.w;
    #pragma unroll
    for (int off = 16; off > 0; off >>= 1) {
        p1 += __shfl_down(p1, off, 32);
        p2 += __shfl_down(p2, off, 32);
    }
    if (ct == 0) { f1[r0] = p1; f2[r0] = p2; }
}

// ---------------- Kernel 2: MFMA attention, 2 waves x 32 rows ---------------
// LDS-redundancy fix: with W waves/block each reading the FULL 8 KB B-tile
// per step, per-CU LDS traffic scales with W. 2 waves x 32 rows halves it
// vs r1's 4 x 16 (96 KB/CU/step vs 160) while total VALU/MFMA is unchanged;
// each b-fragment now feeds 2 MFMAs (row-halves A/B).
// vmcnt ledger (4 gll16/wave/step, ring-4 depth-2, bits uint4 per group with
// 1-group lookahead): younger-than-tile(jt) at the barrier = 10 at phases
// O=0,1 (bits pair in window) and 8 at O=2,3; peel tail 8/8/4/0. Counts are
// reorder-robust: asm fences pin segment boundaries, and within a segment
// the younger-op COUNT w.r.t. an older tile is order-invariant; in-order
// vmcnt retire (suffix property) does the rest. m201 vmcnt-before-barrier
// pattern for cross-wave DMA visibility.
__device__ __forceinline__ float pbit(float f1r, float fv, unsigned byte_,
                                      int u, float& dsum) {
    float s = f1r + fv;
    float e = fmaxf(s, ALPHA * s);        // leaky-relu, branch-free
    float p = (byte_ & (1u << u)) ? __expf(e) : 0.f;
    dsum += p;
    return p;
}

#define VMB10 "s_waitcnt vmcnt(10)\n\ts_barrier"
#define VMB8  "s_waitcnt vmcnt(8)\n\ts_barrier"
#define VMB4  "s_waitcnt vmcnt(4)\n\ts_barrier"
#define VMB0  "s_waitcnt vmcnt(0)\n\ts_barrier"

// O = compile-time step-phase (0..3): read buffer O, prefetch into (O+2)&3.
// WA/WB = bits words for row-halves. JT runtime step idx. ISSG compile-time.
#define K2STEP(WA, WB, O, JT, VMB, ISSG)                                     \
    {                                                                        \
        if (ISSG) {                                                          \
            const char* ws_ = (const char*)WhTb + (size_t)(tile0 + (JT) + 2) * 8192; \
            char* bd_ = (char*)&bsm[((O) + 2) & 3][0] + wv * 4096;           \
            const char* wsw_ = ws_ + wv * 4096 + lsw;                        \
            gll16(wsw_ +    0, bd_ +    0);                                  \
            gll16(wsw_ + 1024, bd_ + 1024);                                  \
            gll16(wsw_ + 2048, bd_ + 2048);                                  \
            gll16(wsw_ + 3072, bd_ + 3072);                                  \
        }                                                                    \
        float4 F0_ = *(const float4*)&f2s[(JT) * 32 + quad * 8];             \
        float4 F1_ = *(const float4*)&f2s[(JT) * 32 + quad * 8 + 4];         \
        unsigned byA_ = ((WA) >> (quad << 3)) & 0xffu;                       \
        unsigned byB_ = ((WB) >> (quad << 3)) & 0xffu;                       \
        float a0_ = pbit(f1A, F0_.x, byA_, 0, dsA);                          \
        float a1_ = pbit(f1A, F0_.y, byA_, 1, dsA);                          \
        float a2_ = pbit(f1A, F0_.z, byA_, 2, dsA);                          \
        float a3_ = pbit(f1A, F0_.w, byA_, 3, dsA);                          \
        float a4_ = pbit(f1A, F1_.x, byA_, 4, dsA);                          \
        float a5_ = pbit(f1A, F1_.y, byA_, 5, dsA);                          \
        float a6_ = pbit(f1A, F1_.z, byA_, 6, dsA);                          \
        float a7_ = pbit(f1A, F1_.w, byA_, 7, dsA);                          \
        float c0_ = pbit(f1B, F0_.x, byB_, 0, dsB);                          \
        float c1_ = pbit(f1B, F0_.y, byB_, 1, dsB);                          \
        float c2_ = pbit(f1B, F0_.z, byB_, 2, dsB);                          \
        float c3_ = pbit(f1B, F0_.w, byB_, 3, dsB);                          \
        float c4_ = pbit(f1B, F1_.x, byB_, 4, dsB);                          \
        float c5_ = pbit(f1B, F1_.y, byB_, 5, dsB);                          \
        float c6_ = pbit(f1B, F1_.z, byB_, 6, dsB);                          \
        float c7_ = pbit(f1B, F1_.w, byB_, 7, dsB);                          \
        union { __hip_bfloat162 hh[4]; bf16x8 v; } pkA_, pkB_;               \
        pkA_.hh[0] = __float22bfloat162_rn(make_float2(a0_, a1_));           \
        pkA_.hh[1] = __float22bfloat162_rn(make_float2(a2_, a3_));           \
        pkA_.hh[2] = __float22bfloat162_rn(make_float2(a4_, a5_));           \
        pkA_.hh[3] = __float22bfloat162_rn(make_float2(a6_, a7_));           \
        pkB_.hh[0] = __float22bfloat162_rn(make_float2(c0_, c1_));           \
        pkB_.hh[1] = __float22bfloat162_rn(make_float2(c2_, c3_));           \
        pkB_.hh[2] = __float22bfloat162_rn(make_float2(c4_, c5_));           \
        pkB_.hh[3] = __float22bfloat162_rn(make_float2(c6_, c7_));           \
        bf16x8 afA = pkA_.v, afB = pkB_.v;                                   \
        asm volatile(VMB ::: "memory");                                      \
        const char* bb_ = (const char*)&bsm[(O)][0] + laneb2;                \
        bf16x8 b0_ = *(const bf16x8*)(bb_);                                  \
        bf16x8 b1_ = *(const bf16x8*)(bb_ + 1024);                           \
        bf16x8 b2_ = *(const bf16x8*)(bb_ + 2048);                           \
        bf16x8 b3_ = *(const bf16x8*)(bb_ + 3072);                           \
        bf16x8 b4_ = *(const bf16x8*)(bb_ + 4096);                           \
        bf16x8 b5_ = *(const bf16x8*)(bb_ + 5120);                           \
        bf16x8 b6_ = *(const bf16x8*)(bb_ + 6144);                           \
        bf16x8 b7_ = *(const bf16x8*)(bb_ + 7168);                           \
        aA0 = __builtin_amdgcn_mfma_f32_16x16x32_bf16(afA, b0_, aA0, 0, 0, 0); \
        aB0 = __builtin_amdgcn_mfma_f32_16x16x32_bf16(afB, b0_, aB0, 0, 0, 0); \
        aA1 = __builtin_amdgcn_mfma_f32_16x16x32_bf16(afA, b1_, aA1, 0, 0, 0); \
        aB1 = __builtin_amdgcn_mfma_f32_16x16x32_bf16(afB, b1_, aB1, 0, 0, 0); \
        aA2 = __builtin_amdgcn_mfma_f32_16x16x32_bf16(afA, b2_, aA2, 0, 0, 0); \
        aB2 = __builtin_amdgcn_mfma_f32_16x16x32_bf16(afB, b2_, aB2, 0, 0, 0); \
        aA3 = __builtin_amdgcn_mfma_f32_16x16x32_bf16(afA, b3_, aA3, 0, 0, 0); \
        aB3 = __builtin_amdgcn_mfma_f32_16x16x32_bf16(afB, b3_, aB3, 0, 0, 0); \
        aA4 = __builtin_amdgcn_mfma_f32_16x16x32_bf16(afA, b4_, aA4, 0, 0, 0); \
        aB4 = __builtin_amdgcn_mfma_f32_16x16x32_bf16(afB, b4_, aB4, 0, 0, 0); \
        aA5 = __builtin_amdgcn_mfma_f32_16x16x32_bf16(afA, b5_, aA5, 0, 0, 0); \
        aB5 = __builtin_amdgcn_mfma_f32_16x16x32_bf16(afB, b5_, aB5, 0, 0, 0); \
        aA6 = __builtin_amdgcn_mfma_f32_16x16x32_bf16(afA, b6_, aA6, 0, 0, 0); \
        aB6 = __builtin_amdgcn_mfma_f32_16x16x32_bf16(afB, b6_, aB6, 0, 0, 0); \
        aA7 = __builtin_amdgcn_mfma_f32_16x16x32_bf16(afA, b7_, aA7, 0, 0, 0); \
        aB7 = __builtin_amdgcn_mfma_f32_16x16x32_bf16(afB, b7_, aB7, 0, 0, 0); \
    }

__global__ __launch_bounds__(128, 2) void k2_attn(
        const unsigned* __restrict__ bits, const unsigned short* __restrict__ WhTb,
        const float* __restrict__ f1, const float* __restrict__ f2,
        float* __restrict__ num, float* __restrict__ den) {
    __shared__ unsigned short bsm[4][4096];   // 4 x 8 KB B-tile ring buffer
    __shared__ float f2s[1024];               // block's f2 span (4 KB)

    const int t    = threadIdx.x;             // 0..127 (2 waves)
    const int wv   = t >> 6;                  // 0..1 : wave -> 32-row half
    const int ln   = t & 63;
    const int m16  = ln & 15;
    const int quad = ln >> 4;
    const int i0   = blockIdx.x * 64;
    const int s    = blockIdx.y;
    const int rowA = i0 + wv * 32 + m16;      // row-half A
    const int rowB = rowA + 16;               // row-half B
    const int tile0 = s * NTS;
    const int j0    = s * (N / JS);
    // B-fragment read offset (XOR-swizzled, verified r1)
    const int laneb2 = m16 * 64 + ((quad ^ ((m16 >> 1) & 3)) << 4);
    // per-lane swizzled SOURCE offset within a 1 KB stage chunk
    const int lsw = (ln * 16) ^ (((ln >> 3) & 3) << 4);

    // stage f2 span (4 KB; 2 float4 per thread) + B tiles 0,1 (async DMA)
    *(float4*)&f2s[t * 4]       = *(const float4*)(f2 + j0 + t * 4);
    *(float4*)&f2s[512 + t * 4] = *(const float4*)(f2 + j0 + 512 + t * 4);
    {
        const char* ws0 = (const char*)WhTb + (size_t)tile0 * 8192 + wv * 4096 + lsw;
        char* bd0 = (char*)&bsm[0][0] + wv * 4096;
        gll16(ws0 +    0, bd0 +    0);
        gll16(ws0 + 1024, bd0 + 1024);
        gll16(ws0 + 2048, bd0 + 2048);
        gll16(ws0 + 3072, bd0 + 3072);
        const char* ws1 = ws0 + 8192;
        char* bd1 = (char*)&bsm[1][0] + wv * 4096;
        gll16(ws1 +    0, bd1 +    0);
        gll16(ws1 + 1024, bd1 + 1024);
        gll16(ws1 + 2048, bd1 + 2048);
        gll16(ws1 + 3072, bd1 + 3072);
    }

    const float f1A = f1[rowA];
    const float f1B = f1[rowB];
    const uint4* browA = (const uint4*)(bits + (size_t)rowA * 256 + tile0);
    const uint4* browB = (const uint4*)(bits + (size_t)rowB * 256 + tile0);

    f32x4 aA0 = {0.f,0.f,0.f,0.f}, aA1 = {0.f,0.f,0.f,0.f};
    f32x4 aA2 = {0.f,0.f,0.f,0.f}, aA3 = {0.f,0.f,0.f,0.f};
    f32x4 aA4 = {0.f,0.f,0.f,0.f}, aA5 = {0.f,0.f,0.f,0.f};
    f32x4 aA6 = {0.f,0.f,0.f,0.f}, aA7 = {0.f,0.f,0.f,0.f};
    f32x4 aB0 = {0.f,0.f,0.f,0.f}, aB1 = {0.f,0.f,0.f,0.f};
    f32x4 aB2 = {0.f,0.f,0.f,0.f}, aB3 = {0.f,0.f,0.f,0.f};
    f32x4 aB4 = {0.f,0.f,0.f,0.f}, aB5 = {0.f,0.f,0.f,0.f};
    f32x4 aB6 = {0.f,0.f,0.f,0.f}, aB7 = {0.f,0.f,0.f,0.f};
    float dsA = 0.f, dsB = 0.f;

    uint4 bwcA = browA[0], bwcB = browB[0];   // bits for group 0 (L2-hot)
    // f2s visible to all waves; tiles 0,1 stay in flight (no vmcnt drain)
    asm volatile("s_waitcnt lgkmcnt(0)\n\ts_barrier" ::: "memory");

    for (int g = 0; g < 7; ++g) {             // steps 0..27
        uint4 bwnA = browA[g + 1], bwnB = browB[g + 1];
        const int jtb = g * 4;
        K2STEP(bwcA.x, bwcB.x, 0, jtb + 0, VMB10, 1)
        K2STEP(bwcA.y, bwcB.y, 1, jtb + 1, VMB10, 1)
        K2STEP(bwcA.z, bwcB.z, 2, jtb + 2, VMB8, 1)
        K2STEP(bwcA.w, bwcB.w, 3, jtb + 3, VMB8, 1)
        bwcA = bwnA; bwcB = bwnB;
    }
    // tail group (steps 28..31): last gll16 at step 29 -> tile 31
    K2STEP(bwcA.x, bwcB.x, 0, 28, VMB8, 1)
    K2STEP(bwcA.y, bwcB.y, 1, 29, VMB8, 1)
    K2STEP(bwcA.z, bwcB.z, 2, 30, VMB4, 0)
    K2STEP(bwcA.w, bwcB.w, 3, 31, VMB0, 0)

    // den partials: reduce over quads
    dsA += __shfl_xor(dsA, 16); dsA += __shfl_xor(dsA, 32);
    dsB += __shfl_xor(dsB, 16); dsB += __shfl_xor(dsB, 32);
    if (quad == 0) {
        den[(size_t)s * N + rowA] = dsA;
        den[(size_t)s * N + rowB] = dsB;
    }

    // num partials: D layout col=lane&15, row=quad*4+reg
    float* np = num + (size_t)s * N * OUTF;
    #pragma unroll
    for (int r = 0; r < 4; ++r) {
        const size_t orA = (size_t)(i0 + wv * 32 + quad * 4 + r) * OUTF;
        np[orA + 0 * 16 + m16] = aA0[r];
        np[orA + 1 * 16 + m16] = aA1[r];
        np[orA + 2 * 16 + m16] = aA2[r];
        np[orA + 3 * 16 + m16] = aA3[r];
        np[orA + 4 * 16 + m16] = aA4[r];
        np[orA + 5 * 16 + m16] = aA5[r];
        np[orA + 6 * 16 + m16] = aA6[r];
        np[orA + 7 * 16 + m16] = aA7[r];
        const size_t orB = orA + (size_t)16 * OUTF;
        np[orB + 0 * 16 + m16] = aB0[r];
        np[orB + 1 * 16 + m16] = aB1[r];
        np[orB + 2 * 16 + m16] = aB2[r];
        np[orB + 3 * 16 + m16] = aB3[r];
        np[orB + 4 * 16 + m16] = aB4[r];
        np[orB + 5 * 16 + m16] = aB5[r];
        np[orB + 6 * 16 + m16] = aB6[r];
        np[orB + 7 * 16 + m16] = aB7[r];
    }
}

// ---------------- Kernel 3: combine JS partials, normalize ----------------
__global__ __launch_bounds__(256) void k3_combine(
        const float* __restrict__ num, const float* __restrict__ den,
        float* __restrict__ out) {
    const int idx = blockIdx.x * 256 + threadIdx.x;   // float4 index
    const int row = idx >> 5;
    const int c4  = (idx & 31) * 4;
    float4 ns = {0.f,0.f,0.f,0.f};
    float  ds = 0.f;
    #pragma unroll
    for (int s = 0; s < JS; ++s) {
        float4 nv = *(const float4*)(num + ((size_t)s * N + row) * OUTF + c4);
        ns.x += nv.x; ns.y += nv.y; ns.z += nv.z; ns.w += nv.w;
        ds += den[(size_t)s * N + row];
    }
    const float inv = 1.0f / ds;
    float4 o = {ns.x * inv, ns.y * inv, ns.z * inv, ns.w * inv};
    *(float4*)(out + (size_t)row * OUTF + c4) = o;
}

extern "C" void kernel_launch(void* const* d_in, const int* in_sizes, int n_in,
                              void* d_out, int out_size, void* d_ws, size_t ws_size,
                              hipStream_t stream) {
    const float* h   = (const float*)d_in[0];   // (8192, 256)
    const int*   adj = (const int*)  d_in[1];   // (8192, 8192)
    const float* W   = (const float*)d_in[2];   // (256, 128)
    const float* a   = (const float*)d_in[3];   // (256, 1)
    float* out = (float*)d_out;                 // (8192, 128)

    unsigned short* WhTb = (unsigned short*)d_ws;          // 2 MB blocked bf16
    float*    f1   = (float*)(WhTb + (size_t)N * OUTF);    // 32 KB
    float*    f2   = f1 + N;                               // 32 KB
    float*    den  = f2 + N;                               // JS*N = 256 KB
    unsigned* bits = (unsigned*)(den + (size_t)JS * N);    // 8 MB
    float*    num  = (float*)(bits + (size_t)N * (N / 32));// JS*N*OUTF = 32 MB

    k01_prep  <<<1024 + (N / 32) * (N / 256), 256, 0, stream>>>(adj, bits, h, W, a, WhTb, f1, f2);
    k2_attn   <<<dim3(N / 64, JS), 128, 0, stream>>>(bits, WhTb, f1, f2, num, den);
    k3_combine<<<(N * OUTF / 4) / 256, 256, 0, stream>>>(num, den, out);
}